// Round 2
// baseline (178.952 us; speedup 1.0000x reference)
//
#include <hip/hip_runtime.h>

#define NN 8192
#define NE 262144
#define DIN 512
#define DOUT 256
#define LRELU_ALPHA 0.2f
#define ROW_CAP 2048

// ---------------- init: zero counters and H_total ----------------
__global__ void init_kernel(int* __restrict__ cnt, float* __restrict__ Htot) {
    int idx = blockIdx.x * 256 + threadIdx.x;
    if (idx < NN) cnt[idx] = 0;
    if (idx < DOUT) Htot[idx] = 0.f;
}

// ---------------- f32 tiled GEMM: H = X @ W ----------------
// X: [NN][DIN] row-major, W: [DIN][DOUT] row-major, H: [NN][DOUT]
__global__ __launch_bounds__(256) void gemm_kernel(const float* __restrict__ X,
                                                   const float* __restrict__ W,
                                                   float* __restrict__ H) {
    __shared__ float As[16][64 + 1];
    __shared__ float Bs[16][64];
    int tid = threadIdx.x;
    int row0 = blockIdx.x * 64;
    int col0 = blockIdx.y * 64;
    int ty = tid >> 4, tx = tid & 15;
    int ar = tid >> 2, ak = (tid & 3) * 4;   // A tile load: 64 rows x 16 k
    int br = tid >> 4, bc = (tid & 15) * 4;  // B tile load: 16 k x 64 cols
    float acc[4][4] = {};
    for (int k0 = 0; k0 < DIN; k0 += 16) {
        float4 av = *(const float4*)(X + (size_t)(row0 + ar) * DIN + k0 + ak);
        As[ak + 0][ar] = av.x;
        As[ak + 1][ar] = av.y;
        As[ak + 2][ar] = av.z;
        As[ak + 3][ar] = av.w;
        float4 bv = *(const float4*)(W + (size_t)(k0 + br) * DOUT + col0 + bc);
        *(float4*)(&Bs[br][bc]) = bv;
        __syncthreads();
#pragma unroll
        for (int kk = 0; kk < 16; ++kk) {
            float a[4], b[4];
#pragma unroll
            for (int u = 0; u < 4; ++u) a[u] = As[kk][ty * 4 + u];
#pragma unroll
            for (int v = 0; v < 4; ++v) b[v] = Bs[kk][tx * 4 + v];
#pragma unroll
            for (int u = 0; u < 4; ++u)
#pragma unroll
                for (int v = 0; v < 4; ++v) acc[u][v] = fmaf(a[u], b[v], acc[u][v]);
        }
        __syncthreads();
    }
#pragma unroll
    for (int u = 0; u < 4; ++u) {
        int r = row0 + ty * 4 + u;
        float4 o = make_float4(acc[u][0], acc[u][1], acc[u][2], acc[u][3]);
        *(float4*)(H + (size_t)r * DOUT + col0 + tx * 4) = o;
    }
}

// ---------------- Wh1/Wh2: per-row dot of H with a[:DOUT], a[DOUT:] ----------------
__global__ __launch_bounds__(256) void wh_kernel(const float* __restrict__ H,
                                                 const float* __restrict__ a,
                                                 float* __restrict__ Wh1,
                                                 float* __restrict__ Wh2) {
    __shared__ float r1[256], r2[256];
    int i = blockIdx.x, d = threadIdx.x;
    float hv = H[(size_t)i * DOUT + d];
    r1[d] = hv * a[d];
    r2[d] = hv * a[DOUT + d];
    __syncthreads();
    for (int ofs = 128; ofs > 0; ofs >>= 1) {
        if (d < ofs) { r1[d] += r1[d + ofs]; r2[d] += r2[d + ofs]; }
        __syncthreads();
    }
    if (d == 0) { Wh1[i] = r1[0]; Wh2[i] = r2[0]; }
}

// ---------------- H_total[d] = sum over all rows of H[r][d] ----------------
__global__ __launch_bounds__(256) void htot_kernel(const float* __restrict__ H,
                                                   float* __restrict__ Htot) {
    int d = threadIdx.x;
    int b = blockIdx.x;  // 64 blocks, 128 rows each
    float acc = 0.f;
    int r0 = b * 128;
    for (int r = r0; r < r0 + 128; ++r) acc += H[(size_t)r * DOUT + d];
    atomicAdd(&Htot[d], acc);
}

// ---------------- edge histogram by row (edge_index passed as int32) ----------------
__global__ void hist_kernel(const int* __restrict__ ei, int* __restrict__ cnt) {
    int e = blockIdx.x * 256 + threadIdx.x;
    if (e < NE) atomicAdd(&cnt[ei[e]], 1);
}

// ---------------- exclusive scan of 8192 counts (1 block / 256 thr) ----------------
__global__ __launch_bounds__(256) void scan_kernel(const int* __restrict__ cnt,
                                                   int* __restrict__ row_start,
                                                   int* __restrict__ cursor) {
    __shared__ int part[256];
    int tid = threadIdx.x;
    int base = tid * 32;
    int ex[32];
    int s = 0;
    for (int j = 0; j < 32; ++j) { ex[j] = s; s += cnt[base + j]; }
    part[tid] = s;
    __syncthreads();
    for (int ofs = 1; ofs < 256; ofs <<= 1) {
        int v = (tid >= ofs) ? part[tid - ofs] : 0;
        __syncthreads();
        part[tid] += v;
        __syncthreads();
    }
    int blockoff = (tid == 0) ? 0 : part[tid - 1];
    for (int j = 0; j < 32; ++j) {
        int v = blockoff + ex[j];
        row_start[base + j] = v;
        cursor[base + j] = v;
    }
}

// ---------------- scatter cols into CSR ----------------
__global__ void scatter_kernel(const int* __restrict__ ei, int* __restrict__ cursor,
                               int* __restrict__ csr_col) {
    int e = blockIdx.x * 256 + threadIdx.x;
    if (e < NE) {
        int r = ei[e];
        int c = ei[NE + e];
        int pos = atomicAdd(&cursor[r], 1);
        csr_col[pos] = c;
    }
}

// ---------------- per-row: dedup, analytic softmax, aggregate, lrelu, L2 norm ----------------
__global__ __launch_bounds__(256) void row_kernel(
    const float* __restrict__ H, const float* __restrict__ Wh1, const float* __restrict__ Wh2,
    const float* __restrict__ Htot, const int* __restrict__ row_start,
    const int* __restrict__ cnt, int* __restrict__ csr_col, float* __restrict__ vv_ws,
    const float* __restrict__ bias, float* __restrict__ out) {
    __shared__ int scols[ROW_CAP];
    __shared__ float svv[ROW_CAP];
    __shared__ float red[256];
    int i = blockIdx.x;
    int tid = threadIdx.x;
    int n = cnt[i];
    int base = row_start[i];
    int* colp;
    float* vvp;
    if (n <= ROW_CAP) {
        colp = scols;
        vvp = svv;
        for (int t = tid; t < n; t += 256) scols[t] = csr_col[base + t];
    } else {  // fallback (never hit for this data, kept for correctness)
        colp = csr_col + base;
        vvp = vv_ws + base;
    }
    __syncthreads();

    const float NEG_INF = -__builtin_inff();
    float wh1 = Wh1[i];
    float localD = 0.f;
    float localm = 0.f;  // baseline 0 from the N-D zero entries
    for (int t = tid; t < n; t += 256) {
        int c = colp[t];
        int k = 0;
        bool first = true;
        for (int q = 0; q < n; ++q) {
            int cq = colp[q];
            k += (cq == c);
            if (cq == c && q < t) first = false;
        }
        float v;
        if (first) {
            float s = wh1 + Wh2[c];
            s = s > 0.f ? s : LRELU_ALPHA * s;
            v = (float)k * s;  // duplicates sum to k * e_ij
            localD += 1.f;
            localm = fmaxf(localm, v);
        } else {
            v = NEG_INF;
        }
        vvp[t] = v;
    }

    // reduce row max (includes baseline 0)
    red[tid] = localm;
    __syncthreads();
    for (int ofs = 128; ofs > 0; ofs >>= 1) {
        if (tid < ofs) red[tid] = fmaxf(red[tid], red[tid + ofs]);
        __syncthreads();
    }
    float m = red[0];
    __syncthreads();

    // reduce distinct count D
    red[tid] = localD;
    __syncthreads();
    for (int ofs = 128; ofs > 0; ofs >>= 1) {
        if (tid < ofs) red[tid] += red[tid + ofs];
        __syncthreads();
    }
    float D = red[0];
    __syncthreads();

    float em = expf(-m);
    float localZ = 0.f;
    for (int t = tid; t < n; t += 256) {
        float v = vvp[t];
        if (v != NEG_INF) localZ += expf(v - m);
    }
    red[tid] = localZ;
    __syncthreads();
    for (int ofs = 128; ofs > 0; ofs >>= 1) {
        if (tid < ofs) red[tid] += red[tid + ofs];
        __syncthreads();
    }
    float Z = red[0] + ((float)NN - D) * em;
    __syncthreads();

    float invZ = 1.f / Z;
    // rewrite vv as aggregation coefficients
    for (int t = tid; t < n; t += 256) {
        float v = vvp[t];
        vvp[t] = (v != NEG_INF) ? (expf(v - m) - em) * invZ : 0.f;
    }
    __syncthreads();

    // h_pass[i][tid]
    float acc = em * invZ * Htot[tid];
    for (int t = 0; t < n; ++t) {
        float c = vvp[t];
        if (c != 0.f) acc = fmaf(c, H[(size_t)colp[t] * DOUT + tid], acc);
    }

    // leaky relu + L2 normalize + bias
    float val = acc > 0.f ? acc : LRELU_ALPHA * acc;
    red[tid] = val * val;
    __syncthreads();
    for (int ofs = 128; ofs > 0; ofs >>= 1) {
        if (tid < ofs) red[tid] += red[tid + ofs];
        __syncthreads();
    }
    float nrm = fmaxf(sqrtf(red[0]), 1e-12f);
    out[(size_t)i * DOUT + tid] = val / nrm + bias[tid];
}

extern "C" void kernel_launch(void* const* d_in, const int* in_sizes, int n_in,
                              void* d_out, int out_size, void* d_ws, size_t ws_size,
                              hipStream_t stream) {
    const float* x = (const float*)d_in[0];
    const int* ei = (const int*)d_in[1];   // int64 in reference -> int32 here
    const float* w = (const float*)d_in[2];
    const float* a = (const float*)d_in[3];
    const float* bias = (const float*)d_in[4];
    float* out = (float*)d_out;

    // workspace layout (floats/ints, all 4B aligned; ~10.2 MB total)
    float* h = (float*)d_ws;            // NN*DOUT
    float* Wh1 = h + (size_t)NN * DOUT; // NN
    float* Wh2 = Wh1 + NN;              // NN
    float* Htot = Wh2 + NN;             // DOUT
    float* vv_ws = Htot + DOUT;         // NE
    int* cnt = (int*)(vv_ws + NE);      // NN
    int* row_start = cnt + NN;          // NN
    int* cursor = row_start + NN;       // NN
    int* csr_col = cursor + NN;         // NE

    init_kernel<<<(NN + 255) / 256 + 1, 256, 0, stream>>>(cnt, Htot);
    gemm_kernel<<<dim3(NN / 64, DOUT / 64), 256, 0, stream>>>(x, w, h);
    hist_kernel<<<NE / 256, 256, 0, stream>>>(ei, cnt);
    wh_kernel<<<NN, 256, 0, stream>>>(h, a, Wh1, Wh2);
    htot_kernel<<<64, 256, 0, stream>>>(h, Htot);
    scan_kernel<<<1, 256, 0, stream>>>(cnt, row_start, cursor);
    scatter_kernel<<<NE / 256, 256, 0, stream>>>(ei, cursor, csr_col);
    row_kernel<<<NN, 256, 0, stream>>>(h, Wh1, Wh2, Htot, row_start, cnt, csr_col, vv_ws,
                                       bias, out);
}

// Round 3
// 122.754 us; speedup vs baseline: 1.4578x; 1.4578x over previous
//
#include <hip/hip_runtime.h>

#define NN 8192
#define NE 262144
#define DIN 512
#define DOUT 256
#define LRELU_ALPHA 0.2f
#define RCAP 256  // per-row col capacity in LDS (Poisson(32) tail @256 ~ 0)

// ---------------- init: zero counters and H_total ----------------
__global__ void init_kernel(int* __restrict__ cnt, float* __restrict__ Htot) {
    int idx = blockIdx.x * 256 + threadIdx.x;
    if (idx < NN) cnt[idx] = 0;
    if (idx < DOUT) Htot[idx] = 0.f;
}

// ---------------- f32 tiled GEMM: H = X @ W ----------------
__global__ __launch_bounds__(256) void gemm_kernel(const float* __restrict__ X,
                                                   const float* __restrict__ W,
                                                   float* __restrict__ H) {
    __shared__ float As[16][64 + 1];
    __shared__ float Bs[16][64];
    int tid = threadIdx.x;
    int row0 = blockIdx.x * 64;
    int col0 = blockIdx.y * 64;
    int ty = tid >> 4, tx = tid & 15;
    int ar = tid >> 2, ak = (tid & 3) * 4;
    int br = tid >> 4, bc = (tid & 15) * 4;
    float acc[4][4] = {};
    for (int k0 = 0; k0 < DIN; k0 += 16) {
        float4 av = *(const float4*)(X + (size_t)(row0 + ar) * DIN + k0 + ak);
        As[ak + 0][ar] = av.x;
        As[ak + 1][ar] = av.y;
        As[ak + 2][ar] = av.z;
        As[ak + 3][ar] = av.w;
        float4 bv = *(const float4*)(W + (size_t)(k0 + br) * DOUT + col0 + bc);
        *(float4*)(&Bs[br][bc]) = bv;
        __syncthreads();
#pragma unroll
        for (int kk = 0; kk < 16; ++kk) {
            float a[4], b[4];
#pragma unroll
            for (int u = 0; u < 4; ++u) a[u] = As[kk][ty * 4 + u];
#pragma unroll
            for (int v = 0; v < 4; ++v) b[v] = Bs[kk][tx * 4 + v];
#pragma unroll
            for (int u = 0; u < 4; ++u)
#pragma unroll
                for (int v = 0; v < 4; ++v) acc[u][v] = fmaf(a[u], b[v], acc[u][v]);
        }
        __syncthreads();
    }
#pragma unroll
    for (int u = 0; u < 4; ++u) {
        int r = row0 + ty * 4 + u;
        float4 o = make_float4(acc[u][0], acc[u][1], acc[u][2], acc[u][3]);
        *(float4*)(H + (size_t)r * DOUT + col0 + tx * 4) = o;
    }
}

// ---------------- Wh1/Wh2: per-row dot of H with a[:DOUT], a[DOUT:] ----------------
__global__ __launch_bounds__(256) void wh_kernel(const float* __restrict__ H,
                                                 const float* __restrict__ a,
                                                 float* __restrict__ Wh1,
                                                 float* __restrict__ Wh2) {
    __shared__ float r1[256], r2[256];
    int i = blockIdx.x, d = threadIdx.x;
    float hv = H[(size_t)i * DOUT + d];
    r1[d] = hv * a[d];
    r2[d] = hv * a[DOUT + d];
    __syncthreads();
    for (int ofs = 128; ofs > 0; ofs >>= 1) {
        if (d < ofs) { r1[d] += r1[d + ofs]; r2[d] += r2[d + ofs]; }
        __syncthreads();
    }
    if (d == 0) { Wh1[i] = r1[0]; Wh2[i] = r2[0]; }
}

// ---------------- H_total[d] = sum over rows of H ----------------
__global__ __launch_bounds__(256) void htot_kernel(const float* __restrict__ H,
                                                   float* __restrict__ Htot) {
    int d = threadIdx.x;
    int b = blockIdx.x;
    float acc = 0.f;
    int r0 = b * 128;
    for (int r = r0; r < r0 + 128; ++r) acc += H[(size_t)r * DOUT + d];
    atomicAdd(&Htot[d], acc);
}

// ---------------- edge histogram by row ----------------
__global__ void hist_kernel(const int* __restrict__ ei, int* __restrict__ cnt) {
    int e = blockIdx.x * 256 + threadIdx.x;
    if (e < NE) atomicAdd(&cnt[ei[e]], 1);
}

// ---------------- exclusive scan of 8192 counts ----------------
__global__ __launch_bounds__(256) void scan_kernel(const int* __restrict__ cnt,
                                                   int* __restrict__ row_start,
                                                   int* __restrict__ cursor) {
    __shared__ int part[256];
    int tid = threadIdx.x;
    int base = tid * 32;
    int ex[32];
    int s = 0;
    for (int j = 0; j < 32; ++j) { ex[j] = s; s += cnt[base + j]; }
    part[tid] = s;
    __syncthreads();
    for (int ofs = 1; ofs < 256; ofs <<= 1) {
        int v = (tid >= ofs) ? part[tid - ofs] : 0;
        __syncthreads();
        part[tid] += v;
        __syncthreads();
    }
    int blockoff = (tid == 0) ? 0 : part[tid - 1];
    for (int j = 0; j < 32; ++j) {
        int v = blockoff + ex[j];
        row_start[base + j] = v;
        cursor[base + j] = v;
    }
}

// ---------------- scatter cols into CSR ----------------
__global__ void scatter_kernel(const int* __restrict__ ei, int* __restrict__ cursor,
                               int* __restrict__ csr_col) {
    int e = blockIdx.x * 256 + threadIdx.x;
    if (e < NE) {
        int r = ei[e];
        int c = ei[NE + e];
        int pos = atomicAdd(&cursor[r], 1);
        csr_col[pos] = c;
    }
}

// ---------------- per-row (one WAVE per row): dedup, analytic softmax, aggregate ----------------
// 4 rows per 256-thread block; lane owns output dims [4*lane, 4*lane+4)
__global__ __launch_bounds__(256) void row_kernel(
    const float* __restrict__ H, const float* __restrict__ Wh1, const float* __restrict__ Wh2,
    const float* __restrict__ Htot, const int* __restrict__ row_start,
    const int* __restrict__ cnt, int* __restrict__ csr_col, float* __restrict__ vv_ws,
    const float* __restrict__ bias, float* __restrict__ out) {
    __shared__ int scols[4][RCAP];
    __shared__ float svv[4][RCAP];
    int tid = threadIdx.x;
    int w = tid >> 6, lane = tid & 63;
    int i = blockIdx.x * 4 + w;
    int n = cnt[i];
    int base = row_start[i];
    bool inlds = (n <= RCAP);
    int* colp = inlds ? scols[w] : (csr_col + base);
    float* vvp = inlds ? svv[w] : (vv_ws + base);
    if (inlds) {
        for (int t = lane; t < n; t += 64) colp[t] = csr_col[base + t];
    }
    __syncthreads();  // cols visible to whole wave (top-level: all 256 threads reach)

    const float NEG_INF = -__builtin_inff();
    float wh1 = Wh1[i];
    float localD = 0.f;
    float localm = 0.f;  // baseline 0 from the NN-D zero entries
    for (int t = lane; t < n; t += 64) {
        int c = colp[t];
        int k = 0;
        bool first = true;
        for (int q = 0; q < n; ++q) {
            int cq = colp[q];
            k += (cq == c);
            if (cq == c && q < t) first = false;
        }
        float v;
        if (first) {
            float s = wh1 + Wh2[c];
            s = s > 0.f ? s : LRELU_ALPHA * s;
            v = (float)k * s;  // duplicates sum to k * e_ij
            localD += 1.f;
            localm = fmaxf(localm, v);
        } else {
            v = NEG_INF;
        }
        vvp[t] = v;
    }

    // wave reductions: row max m, distinct count D
    float m = localm, D = localD;
#pragma unroll
    for (int ofs = 32; ofs > 0; ofs >>= 1) {
        m = fmaxf(m, __shfl_xor(m, ofs));
        D += __shfl_xor(D, ofs);
    }

    float em = expf(-m);
    float localZ = 0.f;
    for (int t = lane; t < n; t += 64) {
        float v = vvp[t];
        if (v != NEG_INF) localZ += expf(v - m);
    }
    float Z = localZ;
#pragma unroll
    for (int ofs = 32; ofs > 0; ofs >>= 1) Z += __shfl_xor(Z, ofs);
    Z += ((float)NN - D) * em;
    float invZ = 1.f / Z;

    // rewrite vv as aggregation coefficients (duplicate slots -> exactly 0)
    for (int t = lane; t < n; t += 64) {
        float v = vvp[t];
        vvp[t] = (v != NEG_INF) ? (expf(v - m) - em) * invZ : 0.f;
    }
    __syncthreads();  // vv/cols visible wave-wide for broadcast reads

    // aggregation: 8 independent accumulators, float4 gathers, no branches
    float4 a4[8];
#pragma unroll
    for (int j = 0; j < 8; ++j) a4[j] = make_float4(0.f, 0.f, 0.f, 0.f);
    int t = 0;
    for (; t + 8 <= n; t += 8) {
#pragma unroll
        for (int j = 0; j < 8; ++j) {
            float wc = vvp[t + j];
            int cc = colp[t + j];
            const float4 hv = *(const float4*)(H + (size_t)cc * DOUT + lane * 4);
            a4[j].x = fmaf(wc, hv.x, a4[j].x);
            a4[j].y = fmaf(wc, hv.y, a4[j].y);
            a4[j].z = fmaf(wc, hv.z, a4[j].z);
            a4[j].w = fmaf(wc, hv.w, a4[j].w);
        }
    }
    for (; t < n; ++t) {
        float wc = vvp[t];
        int cc = colp[t];
        const float4 hv = *(const float4*)(H + (size_t)cc * DOUT + lane * 4);
        a4[0].x = fmaf(wc, hv.x, a4[0].x);
        a4[0].y = fmaf(wc, hv.y, a4[0].y);
        a4[0].z = fmaf(wc, hv.z, a4[0].z);
        a4[0].w = fmaf(wc, hv.w, a4[0].w);
    }
#pragma unroll
    for (int j = 1; j < 8; ++j) {
        a4[0].x += a4[j].x; a4[0].y += a4[j].y; a4[0].z += a4[j].z; a4[0].w += a4[j].w;
    }
    float bc = em * invZ;
    const float4 ht = *(const float4*)(Htot + lane * 4);
    float4 acc = a4[0];
    acc.x = fmaf(bc, ht.x, acc.x);
    acc.y = fmaf(bc, ht.y, acc.y);
    acc.z = fmaf(bc, ht.z, acc.z);
    acc.w = fmaf(bc, ht.w, acc.w);

    // leaky relu
    float4 val;
    val.x = acc.x > 0.f ? acc.x : LRELU_ALPHA * acc.x;
    val.y = acc.y > 0.f ? acc.y : LRELU_ALPHA * acc.y;
    val.z = acc.z > 0.f ? acc.z : LRELU_ALPHA * acc.z;
    val.w = acc.w > 0.f ? acc.w : LRELU_ALPHA * acc.w;

    // L2 norm over the row (wave reduce of per-lane sum of squares)
    float ssq = val.x * val.x + val.y * val.y + val.z * val.z + val.w * val.w;
#pragma unroll
    for (int ofs = 32; ofs > 0; ofs >>= 1) ssq += __shfl_xor(ssq, ofs);
    float inv_nrm = 1.f / fmaxf(sqrtf(ssq), 1e-12f);

    const float4 b4 = *(const float4*)(bias + lane * 4);
    float4 o;
    o.x = fmaf(val.x, inv_nrm, b4.x);
    o.y = fmaf(val.y, inv_nrm, b4.y);
    o.z = fmaf(val.z, inv_nrm, b4.z);
    o.w = fmaf(val.w, inv_nrm, b4.w);
    *(float4*)(out + (size_t)i * DOUT + lane * 4) = o;
}

extern "C" void kernel_launch(void* const* d_in, const int* in_sizes, int n_in,
                              void* d_out, int out_size, void* d_ws, size_t ws_size,
                              hipStream_t stream) {
    const float* x = (const float*)d_in[0];
    const int* ei = (const int*)d_in[1];   // int64 in reference -> int32 here
    const float* w = (const float*)d_in[2];
    const float* a = (const float*)d_in[3];
    const float* bias = (const float*)d_in[4];
    float* out = (float*)d_out;

    float* h = (float*)d_ws;            // NN*DOUT
    float* Wh1 = h + (size_t)NN * DOUT; // NN
    float* Wh2 = Wh1 + NN;              // NN
    float* Htot = Wh2 + NN;             // DOUT
    float* vv_ws = Htot + DOUT;         // NE
    int* cnt = (int*)(vv_ws + NE);      // NN
    int* row_start = cnt + NN;          // NN
    int* cursor = row_start + NN;       // NN
    int* csr_col = cursor + NN;         // NE

    init_kernel<<<(NN + 255) / 256 + 1, 256, 0, stream>>>(cnt, Htot);
    gemm_kernel<<<dim3(NN / 64, DOUT / 64), 256, 0, stream>>>(x, w, h);
    hist_kernel<<<NE / 256, 256, 0, stream>>>(ei, cnt);
    wh_kernel<<<NN, 256, 0, stream>>>(h, a, Wh1, Wh2);
    htot_kernel<<<64, 256, 0, stream>>>(h, Htot);
    scan_kernel<<<1, 256, 0, stream>>>(cnt, row_start, cursor);
    scatter_kernel<<<NE / 256, 256, 0, stream>>>(ei, cursor, csr_col);
    row_kernel<<<NN / 4, 256, 0, stream>>>(h, Wh1, Wh2, Htot, row_start, cnt, csr_col,
                                           vv_ws, bias, out);
}

// Round 4
// 119.487 us; speedup vs baseline: 1.4977x; 1.0273x over previous
//
#include <hip/hip_runtime.h>

#define NN 8192
#define NE 262144
#define DIN 512
#define DOUT 256
#define LRELU_ALPHA 0.2f
#define RCAP 256  // per-row col capacity in LDS (Poisson(32) tail @256 ~ 0)

// ---------------- init: zero counters and H_total ----------------
__global__ void init_kernel(int* __restrict__ cnt, float* __restrict__ Htot) {
    int idx = blockIdx.x * 256 + threadIdx.x;
    if (idx < NN) cnt[idx] = 0;
    if (idx < DOUT) Htot[idx] = 0.f;
}

// ---------------- f32 tiled GEMM: H = X @ W ----------------
// 64x64 tile, K_STEP=32, unpadded k-major LDS so fragment reads are ds_read_b128.
__global__ __launch_bounds__(256) void gemm_kernel(const float* __restrict__ X,
                                                   const float* __restrict__ W,
                                                   float* __restrict__ H) {
    __shared__ float As[32][64];  // k-major, no pad: As[kk][ty*4] is 16B-aligned
    __shared__ float Bs[32][64];
    int tid = threadIdx.x;
    int row0 = blockIdx.x * 64;
    int col0 = blockIdx.y * 64;
    int ty = tid >> 4, tx = tid & 15;
    int ar = tid >> 2, ak = (tid & 3) * 8;  // X: row ar, 8 consecutive k
    int br = tid >> 4, bc = (tid & 15) * 4; // W: rows br, br+16, 4 cols
    float acc[4][4] = {};
    for (int k0 = 0; k0 < DIN; k0 += 32) {
        float4 xa = *(const float4*)(X + (size_t)(row0 + ar) * DIN + k0 + ak);
        float4 xb = *(const float4*)(X + (size_t)(row0 + ar) * DIN + k0 + ak + 4);
        float4 w0 = *(const float4*)(W + (size_t)(k0 + br) * DOUT + col0 + bc);
        float4 w1 = *(const float4*)(W + (size_t)(k0 + br + 16) * DOUT + col0 + bc);
        // transpose-write X fragment (k-major)
        As[ak + 0][ar] = xa.x;
        As[ak + 1][ar] = xa.y;
        As[ak + 2][ar] = xa.z;
        As[ak + 3][ar] = xa.w;
        As[ak + 4][ar] = xb.x;
        As[ak + 5][ar] = xb.y;
        As[ak + 6][ar] = xb.z;
        As[ak + 7][ar] = xb.w;
        *(float4*)&Bs[br][bc] = w0;
        *(float4*)&Bs[br + 16][bc] = w1;
        __syncthreads();
#pragma unroll
        for (int kk = 0; kk < 32; ++kk) {
            float4 a4 = *(const float4*)&As[kk][ty * 4];
            float4 b4 = *(const float4*)&Bs[kk][tx * 4];
            acc[0][0] = fmaf(a4.x, b4.x, acc[0][0]);
            acc[0][1] = fmaf(a4.x, b4.y, acc[0][1]);
            acc[0][2] = fmaf(a4.x, b4.z, acc[0][2]);
            acc[0][3] = fmaf(a4.x, b4.w, acc[0][3]);
            acc[1][0] = fmaf(a4.y, b4.x, acc[1][0]);
            acc[1][1] = fmaf(a4.y, b4.y, acc[1][1]);
            acc[1][2] = fmaf(a4.y, b4.z, acc[1][2]);
            acc[1][3] = fmaf(a4.y, b4.w, acc[1][3]);
            acc[2][0] = fmaf(a4.z, b4.x, acc[2][0]);
            acc[2][1] = fmaf(a4.z, b4.y, acc[2][1]);
            acc[2][2] = fmaf(a4.z, b4.z, acc[2][2]);
            acc[2][3] = fmaf(a4.z, b4.w, acc[2][3]);
            acc[3][0] = fmaf(a4.w, b4.x, acc[3][0]);
            acc[3][1] = fmaf(a4.w, b4.y, acc[3][1]);
            acc[3][2] = fmaf(a4.w, b4.z, acc[3][2]);
            acc[3][3] = fmaf(a4.w, b4.w, acc[3][3]);
        }
        __syncthreads();
    }
#pragma unroll
    for (int u = 0; u < 4; ++u) {
        int r = row0 + ty * 4 + u;
        float4 o = make_float4(acc[u][0], acc[u][1], acc[u][2], acc[u][3]);
        *(float4*)(H + (size_t)r * DOUT + col0 + tx * 4) = o;
    }
}

// ---------------- fused Wh1/Wh2 + H_total: single pass over H ----------------
// 128 blocks x 4 waves; each wave owns 16 rows; lane owns dims [4*lane, 4*lane+4)
__global__ __launch_bounds__(256) void whhtot_kernel(const float* __restrict__ H,
                                                     const float* __restrict__ a,
                                                     float* __restrict__ Wh1,
                                                     float* __restrict__ Wh2,
                                                     float* __restrict__ Htot) {
    __shared__ float hred[4][DOUT];
    int tid = threadIdx.x;
    int w = tid >> 6, lane = tid & 63;
    const float4 a1 = *(const float4*)(a + lane * 4);
    const float4 a2 = *(const float4*)(a + DOUT + lane * 4);
    float4 hsum = make_float4(0.f, 0.f, 0.f, 0.f);
    int r0 = blockIdx.x * 64 + w * 16;
    for (int r = r0; r < r0 + 16; ++r) {
        const float4 hv = *(const float4*)(H + (size_t)r * DOUT + lane * 4);
        hsum.x += hv.x; hsum.y += hv.y; hsum.z += hv.z; hsum.w += hv.w;
        float d1 = hv.x * a1.x + hv.y * a1.y + hv.z * a1.z + hv.w * a1.w;
        float d2 = hv.x * a2.x + hv.y * a2.y + hv.z * a2.z + hv.w * a2.w;
#pragma unroll
        for (int ofs = 32; ofs > 0; ofs >>= 1) {
            d1 += __shfl_xor(d1, ofs);
            d2 += __shfl_xor(d2, ofs);
        }
        if (lane == 0) { Wh1[r] = d1; Wh2[r] = d2; }
    }
    *(float4*)&hred[w][lane * 4] = hsum;
    __syncthreads();
    if (tid < DOUT) {
        float s = hred[0][tid] + hred[1][tid] + hred[2][tid] + hred[3][tid];
        atomicAdd(&Htot[tid], s);
    }
}

// ---------------- edge histogram by row ----------------
__global__ void hist_kernel(const int* __restrict__ ei, int* __restrict__ cnt) {
    int e = blockIdx.x * 256 + threadIdx.x;
    if (e < NE) atomicAdd(&cnt[ei[e]], 1);
}

// ---------------- exclusive scan of 8192 counts ----------------
__global__ __launch_bounds__(256) void scan_kernel(const int* __restrict__ cnt,
                                                   int* __restrict__ row_start,
                                                   int* __restrict__ cursor) {
    __shared__ int part[256];
    int tid = threadIdx.x;
    int base = tid * 32;
    int ex[32];
    int s = 0;
    for (int j = 0; j < 32; ++j) { ex[j] = s; s += cnt[base + j]; }
    part[tid] = s;
    __syncthreads();
    for (int ofs = 1; ofs < 256; ofs <<= 1) {
        int v = (tid >= ofs) ? part[tid - ofs] : 0;
        __syncthreads();
        part[tid] += v;
        __syncthreads();
    }
    int blockoff = (tid == 0) ? 0 : part[tid - 1];
    for (int j = 0; j < 32; ++j) {
        int v = blockoff + ex[j];
        row_start[base + j] = v;
        cursor[base + j] = v;
    }
}

// ---------------- scatter cols into CSR ----------------
__global__ void scatter_kernel(const int* __restrict__ ei, int* __restrict__ cursor,
                               int* __restrict__ csr_col) {
    int e = blockIdx.x * 256 + threadIdx.x;
    if (e < NE) {
        int r = ei[e];
        int c = ei[NE + e];
        int pos = atomicAdd(&cursor[r], 1);
        csr_col[pos] = c;
    }
}

// ---------------- per-row (one WAVE per row): dedup, analytic softmax, aggregate ----------------
__global__ __launch_bounds__(256) void row_kernel(
    const float* __restrict__ H, const float* __restrict__ Wh1, const float* __restrict__ Wh2,
    const float* __restrict__ Htot, const int* __restrict__ row_start,
    const int* __restrict__ cnt, int* __restrict__ csr_col, float* __restrict__ vv_ws,
    const float* __restrict__ bias, float* __restrict__ out) {
    __shared__ int scols[4][RCAP];
    __shared__ float svv[4][RCAP];
    int tid = threadIdx.x;
    int w = tid >> 6, lane = tid & 63;
    int i = blockIdx.x * 4 + w;
    int n = cnt[i];
    int base = row_start[i];
    bool inlds = (n <= RCAP);
    int* colp = inlds ? scols[w] : (csr_col + base);
    float* vvp = inlds ? svv[w] : (vv_ws + base);
    if (inlds) {
        for (int t = lane; t < n; t += 64) colp[t] = csr_col[base + t];
    }
    __syncthreads();

    const float NEG_INF = -__builtin_inff();
    float wh1 = Wh1[i];
    float localD = 0.f;
    float localm = 0.f;  // baseline 0 from the NN-D zero entries
    for (int t = lane; t < n; t += 64) {
        int c = colp[t];
        int k = 0;
        bool first = true;
        for (int q = 0; q < n; ++q) {
            int cq = colp[q];
            k += (cq == c);
            if (cq == c && q < t) first = false;
        }
        float v;
        if (first) {
            float s = wh1 + Wh2[c];
            s = s > 0.f ? s : LRELU_ALPHA * s;
            v = (float)k * s;  // duplicates sum to k * e_ij
            localD += 1.f;
            localm = fmaxf(localm, v);
        } else {
            v = NEG_INF;
        }
        vvp[t] = v;
    }

    float m = localm, D = localD;
#pragma unroll
    for (int ofs = 32; ofs > 0; ofs >>= 1) {
        m = fmaxf(m, __shfl_xor(m, ofs));
        D += __shfl_xor(D, ofs);
    }

    float em = expf(-m);
    float localZ = 0.f;
    for (int t = lane; t < n; t += 64) {
        float v = vvp[t];
        if (v != NEG_INF) localZ += expf(v - m);
    }
    float Z = localZ;
#pragma unroll
    for (int ofs = 32; ofs > 0; ofs >>= 1) Z += __shfl_xor(Z, ofs);
    Z += ((float)NN - D) * em;
    float invZ = 1.f / Z;

    for (int t = lane; t < n; t += 64) {
        float v = vvp[t];
        vvp[t] = (v != NEG_INF) ? (expf(v - m) - em) * invZ : 0.f;
    }
    __syncthreads();

    // aggregation: 8 independent accumulators, float4 gathers, no branches
    float4 a4[8];
#pragma unroll
    for (int j = 0; j < 8; ++j) a4[j] = make_float4(0.f, 0.f, 0.f, 0.f);
    int t = 0;
    for (; t + 8 <= n; t += 8) {
#pragma unroll
        for (int j = 0; j < 8; ++j) {
            float wc = vvp[t + j];
            int cc = colp[t + j];
            const float4 hv = *(const float4*)(H + (size_t)cc * DOUT + lane * 4);
            a4[j].x = fmaf(wc, hv.x, a4[j].x);
            a4[j].y = fmaf(wc, hv.y, a4[j].y);
            a4[j].z = fmaf(wc, hv.z, a4[j].z);
            a4[j].w = fmaf(wc, hv.w, a4[j].w);
        }
    }
    for (; t < n; ++t) {
        float wc = vvp[t];
        int cc = colp[t];
        const float4 hv = *(const float4*)(H + (size_t)cc * DOUT + lane * 4);
        a4[0].x = fmaf(wc, hv.x, a4[0].x);
        a4[0].y = fmaf(wc, hv.y, a4[0].y);
        a4[0].z = fmaf(wc, hv.z, a4[0].z);
        a4[0].w = fmaf(wc, hv.w, a4[0].w);
    }
#pragma unroll
    for (int j = 1; j < 8; ++j) {
        a4[0].x += a4[j].x; a4[0].y += a4[j].y; a4[0].z += a4[j].z; a4[0].w += a4[j].w;
    }
    float bc = em * invZ;
    const float4 ht = *(const float4*)(Htot + lane * 4);
    float4 acc = a4[0];
    acc.x = fmaf(bc, ht.x, acc.x);
    acc.y = fmaf(bc, ht.y, acc.y);
    acc.z = fmaf(bc, ht.z, acc.z);
    acc.w = fmaf(bc, ht.w, acc.w);

    float4 val;
    val.x = acc.x > 0.f ? acc.x : LRELU_ALPHA * acc.x;
    val.y = acc.y > 0.f ? acc.y : LRELU_ALPHA * acc.y;
    val.z = acc.z > 0.f ? acc.z : LRELU_ALPHA * acc.z;
    val.w = acc.w > 0.f ? acc.w : LRELU_ALPHA * acc.w;

    float ssq = val.x * val.x + val.y * val.y + val.z * val.z + val.w * val.w;
#pragma unroll
    for (int ofs = 32; ofs > 0; ofs >>= 1) ssq += __shfl_xor(ssq, ofs);
    float inv_nrm = 1.f / fmaxf(sqrtf(ssq), 1e-12f);

    const float4 b4 = *(const float4*)(bias + lane * 4);
    float4 o;
    o.x = fmaf(val.x, inv_nrm, b4.x);
    o.y = fmaf(val.y, inv_nrm, b4.y);
    o.z = fmaf(val.z, inv_nrm, b4.z);
    o.w = fmaf(val.w, inv_nrm, b4.w);
    *(float4*)(out + (size_t)i * DOUT + lane * 4) = o;
}

extern "C" void kernel_launch(void* const* d_in, const int* in_sizes, int n_in,
                              void* d_out, int out_size, void* d_ws, size_t ws_size,
                              hipStream_t stream) {
    const float* x = (const float*)d_in[0];
    const int* ei = (const int*)d_in[1];   // int64 in reference -> int32 here
    const float* w = (const float*)d_in[2];
    const float* a = (const float*)d_in[3];
    const float* bias = (const float*)d_in[4];
    float* out = (float*)d_out;

    float* h = (float*)d_ws;            // NN*DOUT
    float* Wh1 = h + (size_t)NN * DOUT; // NN
    float* Wh2 = Wh1 + NN;              // NN
    float* Htot = Wh2 + NN;             // DOUT
    float* vv_ws = Htot + DOUT;         // NE
    int* cnt = (int*)(vv_ws + NE);      // NN
    int* row_start = cnt + NN;          // NN
    int* cursor = row_start + NN;       // NN
    int* csr_col = cursor + NN;         // NE

    init_kernel<<<(NN + 255) / 256 + 1, 256, 0, stream>>>(cnt, Htot);
    gemm_kernel<<<dim3(NN / 64, DOUT / 64), 256, 0, stream>>>(x, w, h);
    hist_kernel<<<NE / 256, 256, 0, stream>>>(ei, cnt);
    whhtot_kernel<<<NN / 64, 256, 0, stream>>>(h, a, Wh1, Wh2, Htot);
    scan_kernel<<<1, 256, 0, stream>>>(cnt, row_start, cursor);
    scatter_kernel<<<NE / 256, 256, 0, stream>>>(ei, cursor, csr_col);
    row_kernel<<<NN / 4, 256, 0, stream>>>(h, Wh1, Wh2, Htot, row_start, cnt, csr_col,
                                           vv_ws, bias, out);
}